// Round 8
// baseline (121.577 us; speedup 1.0000x reference)
//
#include <hip/hip_runtime.h>
#include <hip/hip_bf16.h>

#define S_LEN  2048
#define DHEAD  64
#define NHEADS 32
#define NBATCH 4
#define LOG2E  1.44269504f
// fp32(-2^32 * log2e): the one "masked" score in log2 domain. |real scores| << ulp here,
// so score+mask collapses to exactly CMASK, preserving the reference's fp32 semantics
// (all-visible-masked rows become uniform; fixup kernel finishes those).
#define CMASK  (-4294967296.0f * 1.44269504f)

typedef __attribute__((ext_vector_type(4)))  float f4;
typedef __attribute__((ext_vector_type(8)))  short bh8;    // 8 bf16
typedef __attribute__((ext_vector_type(16))) float f16x;   // 32x32 MFMA C/D
typedef __attribute__((ext_vector_type(4)))  int   i4;
typedef __attribute__((ext_vector_type(2)))  int   i2;
typedef unsigned short ushort_t;

static __device__ __forceinline__ unsigned short f2b(float f){
    unsigned int x = __builtin_bit_cast(unsigned int, f);
    x += 0x7FFFu + ((x >> 16) & 1u);
    return (unsigned short)(x >> 16);
}
static __device__ __forceinline__ float b2f(ushort_t u){
    return __builtin_bit_cast(float, ((unsigned)u) << 16);
}
static __device__ __forceinline__ int pack2(float a, float b){
    return (int)((unsigned)f2b(a) | ((unsigned)f2b(b) << 16));
}

// ---- prep: [0,2048) K->bf16 ; [2048,3072) V->bf16 transposed + col partials ;
//      [3072] mask bitwords ----
__global__ __launch_bounds__(256)
void prep(const float* __restrict__ K, const float* __restrict__ V,
          const int* __restrict__ M,
          ushort_t* __restrict__ Kb, ushort_t* __restrict__ Vt,
          float* __restrict__ colpart, unsigned* __restrict__ mbits)
{
    const int bid = blockIdx.x;
    const int tid = threadIdx.x;
    if (bid < 2048){                       // K conversion: 8 floats/thread
        const int i = bid * 256 + tid;
        const f4* p = (const f4*)(K + (size_t)i * 8);
        f4 a = p[0], b = p[1];
        bh8 w;
        #pragma unroll
        for (int k = 0; k < 4; ++k){ w[k] = (short)f2b(a[k]); w[k+4] = (short)f2b(b[k]); }
        *(bh8*)(Kb + (size_t)i * 8) = w;
    } else if (bid < 3072){                // V transpose -> Vt[h][d][s] bf16 (+ column sums)
        __shared__ short T[64][72];
        __shared__ float red[64][4];
        const int r2 = bid - 2048;         // 0..1023 = head*32 + slice
        const int head = r2 >> 5;
        const int kv0  = (r2 & 31) * 64;
        {
            const int r = tid >> 2;
            const int s = (tid & 3) * 16;
            const float* vp = V + ((size_t)head * S_LEN + kv0 + r) * DHEAD + s;
            f4 v0 = *(const f4*)(vp);
            f4 v1 = *(const f4*)(vp + 4);
            f4 v2 = *(const f4*)(vp + 8);
            f4 v3 = *(const f4*)(vp + 12);
            float vv[16];
            *(f4*)&vv[0] = v0; *(f4*)&vv[4] = v1; *(f4*)&vv[8] = v2; *(f4*)&vv[12] = v3;
            #pragma unroll
            for (int i = 0; i < 16; ++i) T[r][s + i] = (short)f2b(vv[i]);
        }
        __syncthreads();
        {
            const int d  = tid >> 2;
            const int k0 = (tid & 3) * 16;
            bh8 w0, w1;
            float s16 = 0.f;
            #pragma unroll
            for (int i = 0; i < 8; ++i){
                w0[i] = T[k0 + i][d];
                w1[i] = T[k0 + 8 + i][d];
                s16 += b2f((ushort_t)w0[i]) + b2f((ushort_t)w1[i]);
            }
            ushort_t* op = Vt + ((size_t)head * DHEAD + d) * S_LEN + kv0 + k0;
            *(bh8*)op       = w0;
            *(bh8*)(op + 8) = w1;
            red[d][tid & 3] = s16;
        }
        __syncthreads();
        if (tid < 64)
            colpart[(size_t)r2 * 64 + tid] =
                red[tid][0] + red[tid][1] + red[tid][2] + red[tid][3];
    } else {                               // mask bitwords: [batch][word], bit j = key masked
        const int* mp = M + ((size_t)(tid >> 6) << 11) + ((tid & 63) << 5);
        unsigned bits = 0u;
        #pragma unroll
        for (int j = 0; j < 32; j += 4){
            i4 v = *(const i4*)(mp + j);
            bits |= (v[0] != 0 ? (1u << j) : 0u) | (v[1] != 0 ? (2u << j) : 0u)
                  | (v[2] != 0 ? (4u << j) : 0u) | (v[3] != 0 ? (8u << j) : 0u);
        }
        mbits[tid] = bits;
    }
}

// ---- main attention: 1 q-tile/block, 4 waves split KV (64 keys/iter), LDS merge ----
__global__ __launch_bounds__(256, 4)
void attn_main(const float* __restrict__ Q, const ushort_t* __restrict__ Kb,
               const ushort_t* __restrict__ Vt, const unsigned* __restrict__ mbits,
               float* __restrict__ Out)
{
    __shared__ char  SMEM[16384];      // loop: 4x 4KB per-wave P buf; epilogue: 2x merge slot
    __shared__ float MM[4][32], ML[4][32];

    const int tid  = threadIdx.x;
    const int wave = tid >> 6;
    const int lane = tid & 63;
    const int lq   = lane & 31;   // q column owned by this lane
    const int hi   = lane >> 5;

    const int bid  = blockIdx.x;
    // heads clustered per XCD (4 heads/XCD -> K+V L2-resident); jq descending (heaviest first)
    const int head = ((bid & 7) << 2) | ((bid >> 3) & 3);
    const int jq   = 63 - (bid >> 5);
    const int b    = head & (NBATCH - 1);
    const int q0   = jq << 5;
    const size_t hoff = (size_t)head * S_LEN * DHEAD;

    char* pw = SMEM + (wave << 12) + (lq << 7);   // this lane's 128-B P row
    const int swz = lq & 7;                       // 3-bit 16B-block XOR swizzle

    // Q B-frags (col=lane&31=q, k=hi*8+j), scale 0.125*log2e folded in
    bh8 qB[4];
    {
        const float* qp = Q + hoff + (size_t)(q0 + lq) * DHEAD;
        const float qs = 0.125f * LOG2E;
        #pragma unroll
        for (int ks = 0; ks < 4; ++ks){
            f4 f0 = *(const f4*)(qp + ks * 16 + hi * 8);
            f4 f1 = *(const f4*)(qp + ks * 16 + hi * 8 + 4);
            bh8 a;
            #pragma unroll
            for (int i = 0; i < 4; ++i){
                a[i]   = (short)f2b(f0[i] * qs);
                a[i+4] = (short)f2b(f1[i] * qs);
            }
            qB[ks] = a;
        }
    }

    f16x acc0 = {};   // O^T rows d=0..31:  col=q=lq, row d=(reg&3)+8*(reg>>2)+4*hi
    f16x acc1 = {};   // O^T rows d=32..63
    float m = -INFINITY, l = 0.f;

    const ushort_t* kbase = Kb + hoff;
    const ushort_t* vbase = Vt + (size_t)head * DHEAD * S_LEN;
    const unsigned* mb = mbits + (b << 6);
    const int jqt = jq >> 1;          // last 64-key tile index
    const int dq  = q0 + lq;          // absolute q row

    for (int kt = wave; kt <= jqt; kt += 4){
        const int kv0 = kt << 6;

        // ---- K frags (2 tiles x 4 k-steps) ----
        bh8 kf[8];
        const ushort_t* kp = kbase + (size_t)(kv0 + lq) * DHEAD + (hi << 3);
        #pragma unroll
        for (int t = 0; t < 2; ++t)
            #pragma unroll
            for (int ks = 0; ks < 4; ++ks)
                kf[t*4+ks] = *(const bh8*)(kp + t * 32 * DHEAD + ks * 16);

        // ---- S^T = K Q^T : two independent MFMA chains ----
        f16x s0 = {}, s1 = {};
        __builtin_amdgcn_s_setprio(1);
        #pragma unroll
        for (int ks = 0; ks < 4; ++ks)
            s0 = __builtin_amdgcn_mfma_f32_32x32x16_bf16(kf[ks],   qB[ks], s0, 0, 0, 0);
        #pragma unroll
        for (int ks = 0; ks < 4; ++ks)
            s1 = __builtin_amdgcn_mfma_f32_32x32x16_bf16(kf[4+ks], qB[ks], s1, 0, 0, 0);
        __builtin_amdgcn_s_setprio(0);

        // ---- V frags issued here: L2 latency hides under softmax ----
        bh8 vf[8];
        const ushort_t* vp = vbase + kv0 + (hi << 3);
        #pragma unroll
        for (int t = 0; t < 2; ++t)
            #pragma unroll
            for (int kk = 0; kk < 2; ++kk){
                vf[t*2+kk]     = *(const bh8*)(vp + (size_t)lq        * S_LEN + t*32 + kk*16);
                vf[4 + t*2+kk] = *(const bh8*)(vp + (size_t)(32 + lq) * S_LEN + t*32 + kk*16);
            }

        // ---- key-padding via wave-uniform bitwords; causal on last tile ----
        // reg g*4+i of tile t -> key kv0 + t*32 + 8g + 4hi + i
        const unsigned ml0 = mb[(kv0 >> 5)    ] >> (hi << 2);
        const unsigned ml1 = mb[(kv0 >> 5) + 1] >> (hi << 2);
        #pragma unroll
        for (int g = 0; g < 4; ++g)
            #pragma unroll
            for (int i = 0; i < 4; ++i){
                s0[g*4+i] = ((ml0 >> (g*8+i)) & 1u) ? CMASK : s0[g*4+i];
                s1[g*4+i] = ((ml1 >> (g*8+i)) & 1u) ? CMASK : s1[g*4+i];
            }
        if (kt == jqt){
            #pragma unroll
            for (int g = 0; g < 4; ++g)
                #pragma unroll
                for (int i = 0; i < 4; ++i){
                    const int k0i = kv0 + (g << 3) + (hi << 2) + i;
                    s0[g*4+i] = (k0i      > dq) ? CMASK : s0[g*4+i];
                    s1[g*4+i] = (k0i + 32 > dq) ? CMASK : s1[g*4+i];
                }
        }

        // ---- row max over 32 scores: local tree + cross-half shfl (R4-verified) ----
        float t8[8];
        #pragma unroll
        for (int i = 0; i < 8; ++i)
            t8[i] = fmaxf(fmaxf(s0[i], s0[i+8]), fmaxf(s1[i], s1[i+8]));
        #pragma unroll
        for (int i = 0; i < 4; ++i) t8[i] = fmaxf(t8[i], t8[i+4]);
        float pml = fmaxf(fmaxf(t8[0], t8[1]), fmaxf(t8[2], t8[3]));
        float pm  = fmaxf(pml, __shfl_xor(pml, 32, 64));

        // ---- deferred rescale (log2 units; 2^11 headroom is bf16/f32-safe) ----
        if (!__all(pm <= m + 11.0f)){
            float mn = fmaxf(m, pm);
            float al = __builtin_amdgcn_exp2f(m - mn);
            m = mn;
            l *= al;
            #pragma unroll
            for (int i = 0; i < 16; ++i){ acc0[i] *= al; acc1[i] *= al; }
        }

        // ---- P = exp2(S - m), row sum ----
        #pragma unroll
        for (int i = 0; i < 16; ++i){
            s0[i] = __builtin_amdgcn_exp2f(s0[i] - m);
            s1[i] = __builtin_amdgcn_exp2f(s1[i] - m);
        }
        float u8[8];
        #pragma unroll
        for (int i = 0; i < 8; ++i) u8[i] = (s0[i] + s0[i+8]) + (s1[i] + s1[i+8]);
        #pragma unroll
        for (int i = 0; i < 4; ++i) u8[i] = u8[i] + u8[i+4];
        float lsl = (u8[0] + u8[1]) + (u8[2] + u8[3]);
        l += lsl + __shfl_xor(lsl, 32, 64);

        // ---- P -> LDS (C-layout) -> B-frags (per-wave buffer, no barrier) ----
        // logical 16B block of key k (0..63): k>>3; physical = logical ^ swz
        #pragma unroll
        for (int g = 0; g < 4; ++g){
            i2 w0, w1;
            w0[0] = pack2(s0[g*4+0], s0[g*4+1]); w0[1] = pack2(s0[g*4+2], s0[g*4+3]);
            w1[0] = pack2(s1[g*4+0], s1[g*4+1]); w1[1] = pack2(s1[g*4+2], s1[g*4+3]);
            *(i2*)(pw + ((g       ^ swz) << 4) + (hi << 3)) = w0;
            *(i2*)(pw + (((4 + g) ^ swz) << 4) + (hi << 3)) = w1;
        }
        asm volatile("s_waitcnt lgkmcnt(0)" ::: "memory");
        __builtin_amdgcn_sched_barrier(0);
        bh8 pa[4];
        #pragma unroll
        for (int t = 0; t < 2; ++t)
            #pragma unroll
            for (int kk = 0; kk < 2; ++kk)
                pa[t*2+kk] = *(const bh8*)(pw + (((t*4 + kk*2 + hi) ^ swz) << 4));

        // ---- O^T += V^T P^T ----
        __builtin_amdgcn_s_setprio(1);
        #pragma unroll
        for (int j = 0; j < 4; ++j){
            acc0 = __builtin_amdgcn_mfma_f32_32x32x16_bf16(vf[j],   pa[j], acc0, 0, 0, 0);
            acc1 = __builtin_amdgcn_mfma_f32_32x32x16_bf16(vf[4+j], pa[j], acc1, 0, 0, 0);
        }
        __builtin_amdgcn_s_setprio(0);
    }

    // ---- 4-way (m,l,O) merge across waves (SMEM reused as 2 merge slots) ----
    if (hi == 0){ MM[wave][lq] = m; ML[wave][lq] = l; }
    __syncthreads();
    float* MGs = (float*)SMEM;
    const float mstar = fmaxf(fmaxf(MM[0][lq], MM[1][lq]), fmaxf(MM[2][lq], MM[3][lq]));
    {
        const float aw = __builtin_amdgcn_exp2f(m - mstar);   // m = -inf (no work) -> 0
        #pragma unroll
        for (int i = 0; i < 16; ++i){ acc0[i] *= aw; acc1[i] *= aw; }
    }
    if (wave & 1){
        float* mg = MGs + (wave >> 1) * 2048;
        #pragma unroll
        for (int i = 0; i < 16; ++i){
            mg[i * 64 + lane]        = acc0[i];
            mg[(16 + i) * 64 + lane] = acc1[i];
        }
    }
    __syncthreads();
    if (!(wave & 1)){
        const float* mg = MGs + (wave >> 1) * 2048;
        #pragma unroll
        for (int i = 0; i < 16; ++i){
            acc0[i] += mg[i * 64 + lane];
            acc1[i] += mg[(16 + i) * 64 + lane];
        }
    }
    __syncthreads();
    if (wave == 2){
        float* mg = MGs;
        #pragma unroll
        for (int i = 0; i < 16; ++i){
            mg[i * 64 + lane]        = acc0[i];
            mg[(16 + i) * 64 + lane] = acc1[i];
        }
    }
    __syncthreads();
    if (wave == 0){
        const float* mg = MGs;
        #pragma unroll
        for (int i = 0; i < 16; ++i){
            acc0[i] += mg[i * 64 + lane];
            acc1[i] += mg[(16 + i) * 64 + lane];
        }
        float lstar = 0.f;
        #pragma unroll
        for (int w = 0; w < 4; ++w)
            lstar += __builtin_amdgcn_exp2f(MM[w][lq] - mstar) * ML[w][lq];
        const float inv = 1.0f / lstar;
        float* op = Out + hoff + (size_t)(q0 + lq) * DHEAD;
        #pragma unroll
        for (int g = 0; g < 4; ++g){
            f4 o0, o1;
            #pragma unroll
            for (int i = 0; i < 4; ++i){
                o0[i] = acc0[g * 4 + i] * inv;
                o1[i] = acc1[g * 4 + i] * inv;
            }
            *(f4*)(op + g * 8 + hi * 4)      = o0;
            *(f4*)(op + 32 + g * 8 + hi * 4) = o1;
        }
    }
}

// Rows q < q* (q* = first unmasked key of the batch): reference softmax is uniform over
// ALL 2048 keys -> output = column mean of V. Reduce prep's 32 partial sums per head.
__global__ __launch_bounds__(256)
void attn_fixup(const float* __restrict__ colpart, const int* __restrict__ M,
                float* __restrict__ Out)
{
    __shared__ float red[4][64];
    __shared__ int qstar;
    const int head = blockIdx.x;
    const int b = head & (NBATCH - 1);
    const int tid = threadIdx.x;
    const int col = tid & 63;
    const int grp = tid >> 6;
    {
        float s = 0.f;
        const float* cp = colpart + ((size_t)head * 32 + grp * 8) * 64 + col;
        #pragma unroll
        for (int j = 0; j < 8; ++j) s += cp[j * 64];
        red[grp][col] = s;
    }
    if (tid == 0){
        int q = 0;
        const int* mp = M + (size_t)b * S_LEN;
        while (q < S_LEN && mp[q]) ++q;
        qstar = q;
    }
    __syncthreads();
    const int qs = qstar;
    if (qs == 0) return;
    const float mean = (red[0][col] + red[1][col] + red[2][col] + red[3][col])
                       * (1.0f / S_LEN);
    for (int q = grp; q < qs; q += 4)
        Out[((size_t)head * S_LEN + q) * DHEAD + col] = mean;
}

extern "C" void kernel_launch(void* const* d_in, const int* in_sizes, int n_in,
                              void* d_out, int out_size, void* d_ws, size_t ws_size,
                              hipStream_t stream)
{
    const float* Q = (const float*)d_in[0];
    const float* K = (const float*)d_in[1];
    const float* V = (const float*)d_in[2];
    const int*   M = (const int*)d_in[3];
    float* Out = (float*)d_out;

    ushort_t* Kb = (ushort_t*)d_ws;                                  // 8.39 MB
    ushort_t* Vt = Kb + (size_t)NHEADS * S_LEN * DHEAD;              // 8.39 MB
    float* colpart = (float*)(Vt + (size_t)NHEADS * S_LEN * DHEAD);  // 256 KB
    unsigned* mbits = (unsigned*)(colpart + 1024 * 64);              // 1 KB

    prep      <<<dim3(3073),   dim3(256), 0, stream>>>(K, V, M, Kb, Vt, colpart, mbits);
    attn_main <<<dim3(2048),   dim3(256), 0, stream>>>(Q, Kb, Vt, mbits, Out);
    attn_fixup<<<dim3(NHEADS), dim3(256), 0, stream>>>(colpart, M, Out);
}

// Round 9
// 80.354 us; speedup vs baseline: 1.5130x; 1.5130x over previous
//
#include <hip/hip_runtime.h>
#include <hip/hip_bf16.h>

#define S_LEN  2048
#define DHEAD  64
#define NHEADS 32
#define NBATCH 4
#define LOG2E  1.44269504f
// fp32(-2^32 * log2e): the one "masked" score in log2 domain. |real scores| << ulp here,
// so score+mask collapses to exactly CMASK, preserving the reference's fp32 semantics
// (all-visible-masked rows become uniform; fixup kernel finishes those).
#define CMASK  (-4294967296.0f * 1.44269504f)

typedef __attribute__((ext_vector_type(4)))  float f4;
typedef __attribute__((ext_vector_type(8)))  short bh8;    // 8 bf16
typedef __attribute__((ext_vector_type(16))) float f16x;   // 32x32 MFMA C/D
typedef __attribute__((ext_vector_type(4)))  int   i4;
typedef __attribute__((ext_vector_type(2)))  int   i2;
typedef unsigned short ushort_t;

static __device__ __forceinline__ unsigned short f2b(float f){
    unsigned int x = __builtin_bit_cast(unsigned int, f);
    x += 0x7FFFu + ((x >> 16) & 1u);
    return (unsigned short)(x >> 16);
}
static __device__ __forceinline__ float b2f(ushort_t u){
    return __builtin_bit_cast(float, ((unsigned)u) << 16);
}
static __device__ __forceinline__ int pack2(float a, float b){
    return (int)((unsigned)f2b(a) | ((unsigned)f2b(b) << 16));
}

// ---- prep: [0,2048) K->bf16 ; [2048,3072) V->bf16 transposed + col partials ;
//      [3072] mask bitwords ----
__global__ __launch_bounds__(256)
void prep(const float* __restrict__ K, const float* __restrict__ V,
          const int* __restrict__ M,
          ushort_t* __restrict__ Kb, ushort_t* __restrict__ Vt,
          float* __restrict__ colpart, unsigned* __restrict__ mbits)
{
    const int bid = blockIdx.x;
    const int tid = threadIdx.x;
    if (bid < 2048){                       // K conversion: 8 floats/thread
        const int i = bid * 256 + tid;
        const f4* p = (const f4*)(K + (size_t)i * 8);
        f4 a = p[0], b = p[1];
        bh8 w;
        #pragma unroll
        for (int k = 0; k < 4; ++k){ w[k] = (short)f2b(a[k]); w[k+4] = (short)f2b(b[k]); }
        *(bh8*)(Kb + (size_t)i * 8) = w;
    } else if (bid < 3072){                // V transpose -> Vt[h][d][s] bf16 (+ column sums)
        __shared__ short T[64][72];
        __shared__ float red[64][4];
        const int r2 = bid - 2048;         // 0..1023 = head*32 + slice
        const int head = r2 >> 5;
        const int kv0  = (r2 & 31) * 64;
        {
            const int r = tid >> 2;
            const int s = (tid & 3) * 16;
            const float* vp = V + ((size_t)head * S_LEN + kv0 + r) * DHEAD + s;
            f4 v0 = *(const f4*)(vp);
            f4 v1 = *(const f4*)(vp + 4);
            f4 v2 = *(const f4*)(vp + 8);
            f4 v3 = *(const f4*)(vp + 12);
            float vv[16];
            *(f4*)&vv[0] = v0; *(f4*)&vv[4] = v1; *(f4*)&vv[8] = v2; *(f4*)&vv[12] = v3;
            #pragma unroll
            for (int i = 0; i < 16; ++i) T[r][s + i] = (short)f2b(vv[i]);
        }
        __syncthreads();
        {
            const int d  = tid >> 2;
            const int k0 = (tid & 3) * 16;
            bh8 w0, w1;
            float s16 = 0.f;
            #pragma unroll
            for (int i = 0; i < 8; ++i){
                w0[i] = T[k0 + i][d];
                w1[i] = T[k0 + 8 + i][d];
                s16 += b2f((ushort_t)w0[i]) + b2f((ushort_t)w1[i]);
            }
            ushort_t* op = Vt + ((size_t)head * DHEAD + d) * S_LEN + kv0 + k0;
            *(bh8*)op       = w0;
            *(bh8*)(op + 8) = w1;
            red[d][tid & 3] = s16;
        }
        __syncthreads();
        if (tid < 64)
            colpart[(size_t)r2 * 64 + tid] =
                red[tid][0] + red[tid][1] + red[tid][2] + red[tid][3];
    } else {                               // mask bitwords: [batch][word], bit j = key masked
        const int* mp = M + ((size_t)(tid >> 6) << 11) + ((tid & 63) << 5);
        unsigned bits = 0u;
        #pragma unroll
        for (int j = 0; j < 32; j += 4){
            i4 v = *(const i4*)(mp + j);
            bits |= (v[0] != 0 ? (1u << j) : 0u) | (v[1] != 0 ? (2u << j) : 0u)
                  | (v[2] != 0 ? (4u << j) : 0u) | (v[3] != 0 ? (8u << j) : 0u);
        }
        mbits[tid] = bits;
    }
}

// ---- main attention: 128-q block (4 waves x 32 q), KV tile 64 double-buffered in LDS
//      via global_load_lds (linear dest + inverse-swizzled source + swizzled ds_read) ----
__global__ __launch_bounds__(256, 2)
void attn_main(const float* __restrict__ Q, const ushort_t* __restrict__ Kb,
               const ushort_t* __restrict__ Vt, const unsigned* __restrict__ mbits,
               float* __restrict__ Out)
{
    __shared__ char Kl[2][8192];   // [key 64][d 128B], row-XOR-swizzled
    __shared__ char Vl[2][8192];   // [d 64][key 128B], row-XOR-swizzled
    __shared__ char Pl[4][4096];   // per-wave P: 32 q-rows x 128B, block-XOR-swizzled

    const int tid  = threadIdx.x;
    const int wave = tid >> 6;
    const int lane = tid & 63;
    const int lq   = lane & 31;   // q column owned by this lane
    const int hi   = lane >> 5;

    const int bid  = blockIdx.x;
    // heads clustered per XCD; j-pairing: bids c and c+256 give constant per-CU tile sum
    const int head = ((bid & 7) << 2) | ((bid >> 3) & 3);
    const int a    = bid >> 5;                       // 0..15
    const int j    = (a < 8) ? (15 - a) : (a - 8);   // 128-row q-block, heaviest first
    const int b    = head & (NBATCH - 1);
    const size_t hoff = (size_t)head * S_LEN * DHEAD;

    const int q0w = (j << 7) + (wave << 5);          // this wave's first q row
    const int dq  = q0w + lq;                        // this lane's q row
    const int td  = q0w >> 6;                        // wave's diagonal KV tile
    const int nt  = (j << 1) + 2;                    // KV tiles for this block

    char* pw = Pl[wave] + (lq << 7);
    const int swz = lq & 7;

    const ushort_t* kbase = Kb + hoff;
    const ushort_t* vbase = Vt + (size_t)head * DHEAD * S_LEN;
    const unsigned* mb = mbits + (b << 6);

    // cooperative stage of one KV tile (K 8KB + V 8KB), coalesced, source pre-swizzled
    auto stage = [&](int buf, int kv0){
        #pragma unroll
        for (int i = 0; i < 2; ++i){
            const int ob  = ((wave << 1) + i) << 10;        // wave-uniform LDS base
            const int o   = ob + (lane << 4);               // this lane's dest byte
            const int row = o >> 7;
            const int cb  = (o & 127) ^ ((row & 7) << 4);   // inverse-swizzled source col
            const char* ks = (const char*)kbase + (size_t)(kv0 + row) * 128 + cb;
            const char* vs = (const char*)vbase + (size_t)row * (S_LEN * 2)
                             + (size_t)kv0 * 2 + cb;
            __builtin_amdgcn_global_load_lds(
                (const __attribute__((address_space(1))) void*)ks,
                (__attribute__((address_space(3))) void*)(&Kl[buf][ob]), 16, 0, 0);
            __builtin_amdgcn_global_load_lds(
                (const __attribute__((address_space(1))) void*)vs,
                (__attribute__((address_space(3))) void*)(&Vl[buf][ob]), 16, 0, 0);
        }
    };

    // Q B-frags (col=lane&31=q, k=hi*8+i), scale 0.125*log2e folded in
    bh8 qB[4];
    {
        const float* qp = Q + hoff + (size_t)(q0w + lq) * DHEAD;
        const float qs = 0.125f * LOG2E;
        #pragma unroll
        for (int ks = 0; ks < 4; ++ks){
            f4 f0 = *(const f4*)(qp + ks * 16 + hi * 8);
            f4 f1 = *(const f4*)(qp + ks * 16 + hi * 8 + 4);
            bh8 aa;
            #pragma unroll
            for (int i = 0; i < 4; ++i){
                aa[i]   = (short)f2b(f0[i] * qs);
                aa[i+4] = (short)f2b(f1[i] * qs);
            }
            qB[ks] = aa;
        }
    }

    f16x acc0 = {};   // O^T rows d=0..31:  col=q=lq, row d=(reg&3)+8*(reg>>2)+4*hi
    f16x acc1 = {};   // O^T rows d=32..63
    float m = -INFINITY, l = 0.f;

    stage(0, 0);
    asm volatile("s_waitcnt vmcnt(0)" ::: "memory");
    __syncthreads();

    for (int t = 0; t < nt; ++t){
        const int cur = t & 1;
        if (t + 1 < nt) stage(cur ^ 1, (t + 1) << 6);

        if (t <= td){
            const int kv0 = t << 6;
            const char* kb = &Kl[cur][0];
            const char* vb = &Vl[cur][0];

            // ---- K A-frags from LDS (swizzled ds_read_b128) ----
            bh8 kf[8];
            #pragma unroll
            for (int t32 = 0; t32 < 2; ++t32)
                #pragma unroll
                for (int ks = 0; ks < 4; ++ks){
                    const int rl = (t32 << 5) + lq;
                    const int cb = ((ks << 5) + (hi << 4)) ^ ((rl & 7) << 4);
                    kf[t32*4+ks] = *(const bh8*)(kb + (rl << 7) + cb);
                }

            // ---- S^T = K Q^T : two independent MFMA chains ----
            f16x s0 = {}, s1 = {};
            __builtin_amdgcn_s_setprio(1);
            #pragma unroll
            for (int ks = 0; ks < 4; ++ks)
                s0 = __builtin_amdgcn_mfma_f32_32x32x16_bf16(kf[ks],   qB[ks], s0, 0, 0, 0);
            #pragma unroll
            for (int ks = 0; ks < 4; ++ks)
                s1 = __builtin_amdgcn_mfma_f32_32x32x16_bf16(kf[4+ks], qB[ks], s1, 0, 0, 0);
            __builtin_amdgcn_s_setprio(0);

            // ---- V A-frags issued here: LDS latency hides under softmax ----
            bh8 vf[8];
            #pragma unroll
            for (int aa = 0; aa < 2; ++aa)
                #pragma unroll
                for (int t32 = 0; t32 < 2; ++t32)
                    #pragma unroll
                    for (int kk = 0; kk < 2; ++kk){
                        const int rl = (aa << 5) + lq;
                        const int cb = ((t32 << 6) + (kk << 5) + (hi << 4))
                                       ^ ((rl & 7) << 4);
                        vf[aa*4 + t32*2 + kk] = *(const bh8*)(vb + (rl << 7) + cb);
                    }

            // ---- key-padding via wave-uniform bitwords; causal on diagonal tile ----
            const unsigned ml0 = mb[(kv0 >> 5)    ] >> (hi << 2);
            const unsigned ml1 = mb[(kv0 >> 5) + 1] >> (hi << 2);
            #pragma unroll
            for (int g = 0; g < 4; ++g)
                #pragma unroll
                for (int i = 0; i < 4; ++i){
                    s0[g*4+i] = ((ml0 >> (g*8+i)) & 1u) ? CMASK : s0[g*4+i];
                    s1[g*4+i] = ((ml1 >> (g*8+i)) & 1u) ? CMASK : s1[g*4+i];
                }
            if (t == td){
                #pragma unroll
                for (int g = 0; g < 4; ++g)
                    #pragma unroll
                    for (int i = 0; i < 4; ++i){
                        const int k0i = kv0 + (g << 3) + (hi << 2) + i;
                        s0[g*4+i] = (k0i      > dq) ? CMASK : s0[g*4+i];
                        s1[g*4+i] = (k0i + 32 > dq) ? CMASK : s1[g*4+i];
                    }
            }

            // ---- row max: local tree + cross-half shfl ----
            float t8[8];
            #pragma unroll
            for (int i = 0; i < 8; ++i)
                t8[i] = fmaxf(fmaxf(s0[i], s0[i+8]), fmaxf(s1[i], s1[i+8]));
            #pragma unroll
            for (int i = 0; i < 4; ++i) t8[i] = fmaxf(t8[i], t8[i+4]);
            float pml = fmaxf(fmaxf(t8[0], t8[1]), fmaxf(t8[2], t8[3]));
            float pm  = fmaxf(pml, __shfl_xor(pml, 32, 64));

            // ---- deferred rescale (log2 units) ----
            if (!__all(pm <= m + 11.0f)){
                float mn = fmaxf(m, pm);
                float al = __builtin_amdgcn_exp2f(m - mn);
                m = mn;
                l *= al;
                #pragma unroll
                for (int i = 0; i < 16; ++i){ acc0[i] *= al; acc1[i] *= al; }
            }

            // ---- P = exp2(S - m), row sum ----
            #pragma unroll
            for (int i = 0; i < 16; ++i){
                s0[i] = __builtin_amdgcn_exp2f(s0[i] - m);
                s1[i] = __builtin_amdgcn_exp2f(s1[i] - m);
            }
            float u8[8];
            #pragma unroll
            for (int i = 0; i < 8; ++i) u8[i] = (s0[i] + s0[i+8]) + (s1[i] + s1[i+8]);
            #pragma unroll
            for (int i = 0; i < 4; ++i) u8[i] = u8[i] + u8[i+4];
            float lsl = (u8[0] + u8[1]) + (u8[2] + u8[3]);
            l += lsl + __shfl_xor(lsl, 32, 64);

            // ---- P -> LDS (C-layout) -> B-frags (per-wave buffer, no barrier) ----
            #pragma unroll
            for (int g = 0; g < 4; ++g){
                i2 w0, w1;
                w0[0] = pack2(s0[g*4+0], s0[g*4+1]); w0[1] = pack2(s0[g*4+2], s0[g*4+3]);
                w1[0] = pack2(s1[g*4+0], s1[g*4+1]); w1[1] = pack2(s1[g*4+2], s1[g*4+3]);
                *(i2*)(pw + ((g       ^ swz) << 4) + (hi << 3)) = w0;
                *(i2*)(pw + (((4 + g) ^ swz) << 4) + (hi << 3)) = w1;
            }
            asm volatile("s_waitcnt lgkmcnt(0)" ::: "memory");
            __builtin_amdgcn_sched_barrier(0);
            bh8 pa[4];
            #pragma unroll
            for (int t32 = 0; t32 < 2; ++t32)
                #pragma unroll
                for (int kk = 0; kk < 2; ++kk)
                    pa[t32*2+kk] = *(const bh8*)(pw + (((t32*4 + kk*2 + hi) ^ swz) << 4));

            // ---- O^T += V^T P^T ----
            __builtin_amdgcn_s_setprio(1);
            #pragma unroll
            for (int jj = 0; jj < 4; ++jj){
                acc0 = __builtin_amdgcn_mfma_f32_32x32x16_bf16(vf[jj],   pa[jj], acc0, 0, 0, 0);
                acc1 = __builtin_amdgcn_mfma_f32_32x32x16_bf16(vf[4+jj], pa[jj], acc1, 0, 0, 0);
            }
            __builtin_amdgcn_s_setprio(0);
        }

        asm volatile("s_waitcnt vmcnt(0)" ::: "memory");   // next tile staged
        __syncthreads();                                    // all waves done with buf[cur]
    }

    // ---- epilogue: O[q][d] = acc/l ; reg g*4+i -> d = 8g+4hi+i ----
    const float inv = 1.0f / l;
    float* op = Out + hoff + (size_t)(q0w + lq) * DHEAD;
    #pragma unroll
    for (int g = 0; g < 4; ++g){
        f4 o0, o1;
        #pragma unroll
        for (int i = 0; i < 4; ++i){
            o0[i] = acc0[g * 4 + i] * inv;
            o1[i] = acc1[g * 4 + i] * inv;
        }
        *(f4*)(op + g * 8 + hi * 4)      = o0;
        *(f4*)(op + 32 + g * 8 + hi * 4) = o1;
    }
}

// Rows q < q* (q* = first unmasked key of the batch): reference softmax is uniform over
// ALL 2048 keys -> output = column mean of V. Reduce prep's 32 partial sums per head.
__global__ __launch_bounds__(256)
void attn_fixup(const float* __restrict__ colpart, const int* __restrict__ M,
                float* __restrict__ Out)
{
    __shared__ float red[4][64];
    __shared__ int qstar;
    const int head = blockIdx.x;
    const int b = head & (NBATCH - 1);
    const int tid = threadIdx.x;
    const int col = tid & 63;
    const int grp = tid >> 6;
    {
        float s = 0.f;
        const float* cp = colpart + ((size_t)head * 32 + grp * 8) * 64 + col;
        #pragma unroll
        for (int j = 0; j < 8; ++j) s += cp[j * 64];
        red[grp][col] = s;
    }
    if (tid == 0){
        int q = 0;
        const int* mp = M + (size_t)b * S_LEN;
        while (q < S_LEN && mp[q]) ++q;
        qstar = q;
    }
    __syncthreads();
    const int qs = qstar;
    if (qs == 0) return;
    const float mean = (red[0][col] + red[1][col] + red[2][col] + red[3][col])
                       * (1.0f / S_LEN);
    for (int q = grp; q < qs; q += 4)
        Out[((size_t)head * S_LEN + q) * DHEAD + col] = mean;
}

extern "C" void kernel_launch(void* const* d_in, const int* in_sizes, int n_in,
                              void* d_out, int out_size, void* d_ws, size_t ws_size,
                              hipStream_t stream)
{
    const float* Q = (const float*)d_in[0];
    const float* K = (const float*)d_in[1];
    const float* V = (const float*)d_in[2];
    const int*   M = (const int*)d_in[3];
    float* Out = (float*)d_out;

    ushort_t* Kb = (ushort_t*)d_ws;                                  // 8.39 MB
    ushort_t* Vt = Kb + (size_t)NHEADS * S_LEN * DHEAD;              // 8.39 MB
    float* colpart = (float*)(Vt + (size_t)NHEADS * S_LEN * DHEAD);  // 256 KB
    unsigned* mbits = (unsigned*)(colpart + 1024 * 64);              // 1 KB

    prep      <<<dim3(3073),   dim3(256), 0, stream>>>(K, V, M, Kb, Vt, colpart, mbits);
    attn_main <<<dim3(512),    dim3(256), 0, stream>>>(Q, Kb, Vt, mbits, Out);
    attn_fixup<<<dim3(NHEADS), dim3(256), 0, stream>>>(colpart, M, Out);
}